// Round 4
// baseline (313.279 us; speedup 1.0000x reference)
//
#include <hip/hip_runtime.h>

#define NDF 96            // feature dim
#define NCH 24            // float4 chunks per feature row (96/4)

// ---------------- CSR build ----------------

__global__ void k_zero(int* __restrict__ deg, int* __restrict__ cursor, int n) {
    int i = blockIdx.x * blockDim.x + threadIdx.x;
    if (i < n) { deg[i] = 0; cursor[i] = 0; }
}

__global__ void k_count(const int* __restrict__ dst, int E, int* __restrict__ deg) {
    int e = blockIdx.x * blockDim.x + threadIdx.x;
    if (e < E) atomicAdd(&deg[dst[e]], 1);
}

// Single-block exclusive scan over n values (hybrid shfl + LDS wave-sum scan).
__global__ void __launch_bounds__(1024) k_scan(const int* __restrict__ deg,
                                               int* __restrict__ row_ptr, int n) {
    __shared__ int wsum[16];
    __shared__ int carry_s;
    int tid  = threadIdx.x;      // 0..1023
    int lane = tid & 63;
    int wid  = tid >> 6;         // 0..15
    if (tid == 0) carry_s = 0;
    __syncthreads();
    for (int base = 0; base < n; base += 1024) {
        int i = base + tid;
        int x = (i < n) ? deg[i] : 0;
        int val = x;
        #pragma unroll
        for (int off = 1; off < 64; off <<= 1) {
            int t = __shfl_up(val, off, 64);
            if (lane >= off) val += t;
        }
        if (lane == 63) wsum[wid] = val;
        __syncthreads();
        if (wid == 0) {
            int w = (lane < 16) ? wsum[lane] : 0;
            #pragma unroll
            for (int off = 1; off < 16; off <<= 1) {
                int t = __shfl_up(w, off, 64);
                if (lane >= off) w += t;
            }
            if (lane < 16) wsum[lane] = w;   // inclusive per-wave prefix sums
        }
        __syncthreads();
        int wave_off = (wid > 0) ? wsum[wid - 1] : 0;
        int incl = val + wave_off;
        if (i < n) row_ptr[i] = carry_s + incl - x;   // exclusive
        __syncthreads();                               // all carry_s reads done
        if (tid == 1023) carry_s += wsum[15];          // chunk total
        __syncthreads();
    }
    if (tid == 0) row_ptr[n] = carry_s;
}

__global__ void k_norms(const int* __restrict__ deg, float* __restrict__ ds,
                        float* __restrict__ dinv, int n) {
    int i = blockIdx.x * blockDim.x + threadIdx.x;
    if (i < n) {
        float d = (float)deg[i];     // deg >= 1 (self-loops)
        ds[i]   = rsqrtf(d);
        dinv[i] = 1.0f / d;
    }
}

__global__ void k_fill(const int* __restrict__ src, const int* __restrict__ dst, int E,
                       const int* __restrict__ row_ptr, int* __restrict__ cursor,
                       int* __restrict__ csr_src) {
    int e = blockIdx.x * blockDim.x + threadIdx.x;
    if (e < E) {
        int d = dst[e];
        int p = atomicAdd(&cursor[d], 1);
        csr_src[row_ptr[d] + p] = src[e];
    }
}

// ---------------- feature pipeline ----------------

// hs0 = F * d^{-1/2}
__global__ void k_scale(const float* __restrict__ feat, const float* __restrict__ ds,
                        float* __restrict__ hs, int nt /* = n*NCH */) {
    int t = blockIdx.x * blockDim.x + threadIdx.x;
    if (t < nt) {
        int v = t / NCH;
        float4 f = ((const float4*)feat)[t];
        float s = ds[v];
        ((float4*)hs)[t] = make_float4(f.x * s, f.y * s, f.z * s, f.w * s);
    }
}

// One propagation round: out-chunk(v,c) = g( sum_{s in N(v)} hs[s][c] )
//   h_new = acc * ds[v] + feat * dinv[v]
//   LAST=0: write hs_next = h_new * ds[v];  LAST=1: write h_new (final output)
template <int LAST>
__global__ void __launch_bounds__(256) k_prop(
        const float* __restrict__ hs, const int* __restrict__ row_ptr,
        const int* __restrict__ csr_src, const float* __restrict__ ds,
        const float* __restrict__ dinv, const float* __restrict__ feat,
        float* __restrict__ out, int nt /* = n*NCH */) {
    int t = blockIdx.x * blockDim.x + threadIdx.x;
    if (t >= nt) return;
    int v = t / NCH;
    int c = t - v * NCH;
    int beg = row_ptr[v];
    int end = row_ptr[v + 1];
    const float4* __restrict__ hs4 = (const float4*)hs;
    float4 acc = make_float4(0.f, 0.f, 0.f, 0.f);
    for (int j = beg; j < end; ++j) {
        int s = csr_src[j];                 // wave-broadcast across the 24 chunk threads
        float4 hv = hs4[s * NCH + c];       // coalesced 384B row per neighbor
        acc.x += hv.x; acc.y += hv.y; acc.z += hv.z; acc.w += hv.w;
    }
    float sv = ds[v];
    float iv = dinv[v];
    float4 f = ((const float4*)feat)[t];
    float4 r;
    r.x = acc.x * sv + f.x * iv;
    r.y = acc.y * sv + f.y * iv;
    r.z = acc.z * sv + f.z * iv;
    r.w = acc.w * sv + f.w * iv;
    if (!LAST) {
        r.x *= sv; r.y *= sv; r.z *= sv; r.w *= sv;
    }
    ((float4*)out)[t] = r;
}

// ---------------- launch ----------------

extern "C" void kernel_launch(void* const* d_in, const int* in_sizes, int n_in,
                              void* d_out, int out_size, void* d_ws, size_t ws_size,
                              hipStream_t stream) {
    const int*   src  = (const int*)d_in[0];
    const int*   dst  = (const int*)d_in[1];
    const float* feat = (const float*)d_in[2];
    const int E = in_sizes[0];
    const int n = in_sizes[2] / NDF;
    float* out = (float*)d_out;

    // workspace carve-up (256B aligned)
    char* p = (char*)d_ws;
    auto take = [&](size_t bytes) {
        char* r = p;
        p += (bytes + 255) & ~size_t(255);
        return r;
    };
    int*   deg     = (int*)  take((size_t)n * 4);
    int*   cursor  = (int*)  take((size_t)n * 4);
    int*   row_ptr = (int*)  take((size_t)(n + 1) * 4);
    float* dsn     = (float*)take((size_t)n * 4);
    float* dinvn   = (float*)take((size_t)n * 4);
    int*   csr     = (int*)  take((size_t)E * 4);
    float* hsA     = (float*)take((size_t)n * NDF * 4);
    float* hsB     = (float*)take((size_t)n * NDF * 4);
    (void)ws_size;

    const int nt = n * NCH;           // float4 elements in a feature matrix
    const int bN  = (n  + 255) / 256;
    const int bE  = (E  + 255) / 256;
    const int bT  = (nt + 255) / 256;

    // CSR build (redone every call; deterministic work)
    k_zero <<<bN, 256, 0, stream>>>(deg, cursor, n);
    k_count<<<bE, 256, 0, stream>>>(dst, E, deg);
    k_scan <<<1, 1024, 0, stream>>>(deg, row_ptr, n);
    k_norms<<<bN, 256, 0, stream>>>(deg, dsn, dinvn, n);
    k_fill <<<bE, 256, 0, stream>>>(src, dst, E, row_ptr, cursor, csr);

    // hs0 = F * d^{-1/2}
    k_scale<<<bT, 256, 0, stream>>>(feat, dsn, hsA, nt);

    // K = 3 propagation rounds (ping-pong hsA/hsB, final round writes d_out)
    k_prop<0><<<bT, 256, 0, stream>>>(hsA, row_ptr, csr, dsn, dinvn, feat, hsB, nt);
    k_prop<0><<<bT, 256, 0, stream>>>(hsB, row_ptr, csr, dsn, dinvn, feat, hsA, nt);
    k_prop<1><<<bT, 256, 0, stream>>>(hsA, row_ptr, csr, dsn, dinvn, feat, out, nt);
}

// Round 5
// 227.126 us; speedup vs baseline: 1.3793x; 1.3793x over previous
//
#include <hip/hip_runtime.h>

#define NDF 96            // feature dim
#define NCHB 12           // ushort8 (8-feat) chunks per bf16 feature row (96/8)

typedef unsigned short u16x8 __attribute__((ext_vector_type(8)));

__device__ __forceinline__ float bf2f(unsigned short u) {
    union { unsigned int i; float f; } x;
    x.i = ((unsigned int)u) << 16;
    return x.f;
}
__device__ __forceinline__ unsigned short f2bf(float f) {
    union { float f; unsigned int i; } x;
    x.f = f;
    unsigned int i = x.i;
    return (unsigned short)((i + 0x7FFFu + ((i >> 16) & 1u)) >> 16);  // RNE
}

// ---------------- CSR build ----------------

__global__ void k_zero(int* __restrict__ deg, int n) {
    int i = blockIdx.x * blockDim.x + threadIdx.x;
    if (i < n) deg[i] = 0;
}

__global__ void k_count(const int* __restrict__ dst, int E, int* __restrict__ deg) {
    int e = blockIdx.x * blockDim.x + threadIdx.x;
    if (e < E) atomicAdd(&deg[dst[e]], 1);
}

// Block-local exclusive scan: row_ptr[i] = local exclusive prefix (within this
// 1024-chunk); blk_sums[blockIdx] = chunk total.
__global__ void __launch_bounds__(1024) k_scan_blk(const int* __restrict__ deg, int n,
                                                   int* __restrict__ row_ptr,
                                                   int* __restrict__ blk_sums) {
    __shared__ int wsum[16];
    int tid  = threadIdx.x;
    int lane = tid & 63;
    int wid  = tid >> 6;
    int i = blockIdx.x * 1024 + tid;
    int x = (i < n) ? deg[i] : 0;
    int val = x;
    #pragma unroll
    for (int off = 1; off < 64; off <<= 1) {
        int t = __shfl_up(val, off, 64);
        if (lane >= off) val += t;
    }
    if (lane == 63) wsum[wid] = val;
    __syncthreads();
    if (wid == 0) {
        int w = (lane < 16) ? wsum[lane] : 0;
        #pragma unroll
        for (int off = 1; off < 16; off <<= 1) {
            int t = __shfl_up(w, off, 64);
            if (lane >= off) w += t;
        }
        if (lane < 16) wsum[lane] = w;   // inclusive per-wave prefix sums
    }
    __syncthreads();
    int wave_off = (wid > 0) ? wsum[wid - 1] : 0;
    if (i < n) row_ptr[i] = val + wave_off - x;     // local exclusive
    if (tid == 0) blk_sums[blockIdx.x] = wsum[15];  // chunk total
}

// Single-wave exclusive scan of block sums (nblk values, looped with carry).
__global__ void __launch_bounds__(64) k_scan_top(const int* __restrict__ blk_sums,
                                                 int* __restrict__ blk_off, int nblk) {
    int lane = threadIdx.x;
    int carry = 0;
    for (int base = 0; base < nblk; base += 64) {
        int i = base + lane;
        int x = (i < nblk) ? blk_sums[i] : 0;
        int val = x;
        #pragma unroll
        for (int off = 1; off < 64; off <<= 1) {
            int t = __shfl_up(val, off, 64);
            if (lane >= off) val += t;
        }
        if (i < nblk) blk_off[i] = carry + val - x;
        carry += __shfl(val, 63, 64);
    }
}

// Fused: finalize row_ptr (+block offset), init cursor copy, compute norms.
__global__ void k_finish(const int* __restrict__ deg, const int* __restrict__ blk_off,
                         int* __restrict__ row_ptr, int* __restrict__ cursor,
                         float* __restrict__ ds, float* __restrict__ dinv,
                         int n, int E) {
    int i = blockIdx.x * blockDim.x + threadIdx.x;
    if (i < n) {
        int val = row_ptr[i] + blk_off[i >> 10];
        row_ptr[i] = val;
        cursor[i]  = val;
        float d = (float)deg[i];          // deg >= 1 (self-loops)
        ds[i]   = rsqrtf(d);
        dinv[i] = 1.0f / d;
    }
    if (i == 0) row_ptr[n] = E;
}

__global__ void k_fill(const int* __restrict__ src, const int* __restrict__ dst, int E,
                       int* __restrict__ cursor, int* __restrict__ csr_src) {
    int e = blockIdx.x * blockDim.x + threadIdx.x;
    if (e < E) {
        int p = atomicAdd(&cursor[dst[e]], 1);   // cursor starts at row_ptr[d]
        csr_src[p] = src[e];
    }
}

// ---------------- feature pipeline ----------------

// hs0 = bf16(F * d^{-1/2}),  hinit = bf16(F * d^{-1})
__global__ void __launch_bounds__(256) k_scale(
        const float* __restrict__ feat, const float* __restrict__ ds,
        const float* __restrict__ dinv, unsigned short* __restrict__ hs,
        unsigned short* __restrict__ hinit, int nt /* = n*NCHB */) {
    int t = blockIdx.x * blockDim.x + threadIdx.x;
    if (t >= nt) return;
    int v = t / NCHB;
    const float4* f4 = (const float4*)feat;
    float4 fa = f4[t * 2];
    float4 fb = f4[t * 2 + 1];
    float s = ds[v];
    float iv = dinv[v];
    u16x8 o, oi;
    o[0] = f2bf(fa.x * s);  oi[0] = f2bf(fa.x * iv);
    o[1] = f2bf(fa.y * s);  oi[1] = f2bf(fa.y * iv);
    o[2] = f2bf(fa.z * s);  oi[2] = f2bf(fa.z * iv);
    o[3] = f2bf(fa.w * s);  oi[3] = f2bf(fa.w * iv);
    o[4] = f2bf(fb.x * s);  oi[4] = f2bf(fb.x * iv);
    o[5] = f2bf(fb.y * s);  oi[5] = f2bf(fb.y * iv);
    o[6] = f2bf(fb.z * s);  oi[6] = f2bf(fb.z * iv);
    o[7] = f2bf(fb.w * s);  oi[7] = f2bf(fb.w * iv);
    ((u16x8*)hs)[t]    = o;
    ((u16x8*)hinit)[t] = oi;
}

// One propagation round. Thread = (node v, 8-feat chunk c).
//   h_new = (sum_{s in N(v)} hs[s]) * ds[v] + hinit[v]
//   LAST=0: write bf16(h_new * ds[v]) to outbf;  LAST=1: write fp32 h_new to out.
template <int LAST>
__global__ void __launch_bounds__(256) k_prop(
        const unsigned short* __restrict__ hs, const int* __restrict__ row_ptr,
        const int* __restrict__ csr_src, const float* __restrict__ ds,
        const unsigned short* __restrict__ hinit,
        void* __restrict__ outp, int nt /* = n*NCHB */) {
    int t = blockIdx.x * blockDim.x + threadIdx.x;
    if (t >= nt) return;
    int v = t / NCHB;
    int c = t - v * NCHB;
    int beg = row_ptr[v];
    int end = row_ptr[v + 1];
    const u16x8* __restrict__ hs8 = (const u16x8*)hs;
    float a0 = 0.f, a1 = 0.f, a2 = 0.f, a3 = 0.f;
    float a4 = 0.f, a5 = 0.f, a6 = 0.f, a7 = 0.f;
    for (int j = beg; j < end; ++j) {
        int s = csr_src[j];                 // ~same addr across the node's 12 lanes
        u16x8 hv = hs8[s * NCHB + c];       // 16B of a contiguous 192B row
        a0 += bf2f(hv[0]); a1 += bf2f(hv[1]);
        a2 += bf2f(hv[2]); a3 += bf2f(hv[3]);
        a4 += bf2f(hv[4]); a5 += bf2f(hv[5]);
        a6 += bf2f(hv[6]); a7 += bf2f(hv[7]);
    }
    float sv = ds[v];
    u16x8 hi = ((const u16x8*)hinit)[t];
    float r0 = a0 * sv + bf2f(hi[0]);
    float r1 = a1 * sv + bf2f(hi[1]);
    float r2 = a2 * sv + bf2f(hi[2]);
    float r3 = a3 * sv + bf2f(hi[3]);
    float r4 = a4 * sv + bf2f(hi[4]);
    float r5 = a5 * sv + bf2f(hi[5]);
    float r6 = a6 * sv + bf2f(hi[6]);
    float r7 = a7 * sv + bf2f(hi[7]);
    if (LAST) {
        float4* o4 = (float4*)outp;
        o4[t * 2]     = make_float4(r0, r1, r2, r3);
        o4[t * 2 + 1] = make_float4(r4, r5, r6, r7);
    } else {
        u16x8 o;
        o[0] = f2bf(r0 * sv); o[1] = f2bf(r1 * sv);
        o[2] = f2bf(r2 * sv); o[3] = f2bf(r3 * sv);
        o[4] = f2bf(r4 * sv); o[5] = f2bf(r5 * sv);
        o[6] = f2bf(r6 * sv); o[7] = f2bf(r7 * sv);
        ((u16x8*)outp)[t] = o;
    }
}

// ---------------- launch ----------------

extern "C" void kernel_launch(void* const* d_in, const int* in_sizes, int n_in,
                              void* d_out, int out_size, void* d_ws, size_t ws_size,
                              hipStream_t stream) {
    const int*   src  = (const int*)d_in[0];
    const int*   dst  = (const int*)d_in[1];
    const float* feat = (const float*)d_in[2];
    const int E = in_sizes[0];
    const int n = in_sizes[2] / NDF;
    float* out = (float*)d_out;

    // workspace carve-up (256B aligned)
    char* p = (char*)d_ws;
    auto take = [&](size_t bytes) {
        char* r = p;
        p += (bytes + 255) & ~size_t(255);
        return r;
    };
    const int nblk = (n + 1023) / 1024;
    int*   deg      = (int*)  take((size_t)n * 4);
    int*   cursor   = (int*)  take((size_t)n * 4);
    int*   row_ptr  = (int*)  take((size_t)(n + 1) * 4);
    int*   blk_sums = (int*)  take((size_t)nblk * 4);
    int*   blk_off  = (int*)  take((size_t)nblk * 4);
    float* dsn      = (float*)take((size_t)n * 4);
    float* dinvn    = (float*)take((size_t)n * 4);
    int*   csr      = (int*)  take((size_t)E * 4);
    unsigned short* hsA   = (unsigned short*)take((size_t)n * NDF * 2);
    unsigned short* hsB   = (unsigned short*)take((size_t)n * NDF * 2);
    unsigned short* hinit = (unsigned short*)take((size_t)n * NDF * 2);
    (void)ws_size;

    const int nt  = n * NCHB;         // ushort8 chunks in a feature matrix
    const int bN  = (n  + 255) / 256;
    const int bE  = (E  + 255) / 256;
    const int bT  = (nt + 255) / 256;

    // CSR build (redone every call; deterministic work)
    k_zero    <<<bN, 256, 0, stream>>>(deg, n);
    k_count   <<<bE, 256, 0, stream>>>(dst, E, deg);
    k_scan_blk<<<nblk, 1024, 0, stream>>>(deg, n, row_ptr, blk_sums);
    k_scan_top<<<1, 64, 0, stream>>>(blk_sums, blk_off, nblk);
    k_finish  <<<bN, 256, 0, stream>>>(deg, blk_off, row_ptr, cursor, dsn, dinvn, n, E);
    k_fill    <<<bE, 256, 0, stream>>>(src, dst, E, cursor, csr);

    // hs0 = bf16(F * d^-1/2), hinit = bf16(F * d^-1)
    k_scale<<<bT, 256, 0, stream>>>(feat, dsn, dinvn, hsA, hinit, nt);

    // K = 3 propagation rounds (ping-pong hsA/hsB, final round writes d_out)
    k_prop<0><<<bT, 256, 0, stream>>>(hsA, row_ptr, csr, dsn, hinit, hsB, nt);
    k_prop<0><<<bT, 256, 0, stream>>>(hsB, row_ptr, csr, dsn, hinit, hsA, nt);
    k_prop<1><<<bT, 256, 0, stream>>>(hsA, row_ptr, csr, dsn, hinit, out, nt);
}